// Round 16
// baseline (717.345 us; speedup 1.0000x reference)
//
#include <hip/hip_runtime.h>
#include <hip/hip_bf16.h>
#include <stdint.h>

#define D_IN    512
#define NTOT    32896
#define BATCH   4096
#define NWG_GEMM 8224   // 32 m-tiles * 257 n-tiles
#define NWG_CONVW 2056  // (64 * 32896/4) / 256  (vectorized: 4 n per thread)
#define NWG_CONVX 1024  // (4096*512/8)/256

typedef __attribute__((ext_vector_type(8))) short short8;
typedef __attribute__((ext_vector_type(4))) float f32x4;

__device__ __forceinline__ unsigned short f2bf(float f) {
    union { float f; uint32_t u; } v; v.f = f;
    return (unsigned short)((v.u + 0x7fffu + ((v.u >> 16) & 1u)) >> 16);
}

// Fused conversion. Blocks [0, NWG_CONVW): W -> k-packed bf16, vectorized.
// Blocks [NWG_CONVW, +NWG_CONVX): x -> bf16.
__global__ __launch_bounds__(256) void conv_fused(const float* __restrict__ x,
                                                  const float* __restrict__ W,
                                                  unsigned short* __restrict__ xb,
                                                  unsigned short* __restrict__ wp) {
    const int b = (int)blockIdx.x;
    if (b < NWG_CONVW) {
        // Wp[g][n][r] = W[g*8+r][n]; thread handles (g, n4..n4+3)
        int tid = b * 256 + (int)threadIdx.x;
        int g   = tid / (NTOT / 4);
        int n4  = (tid - g * (NTOT / 4)) * 4;
        const float* src = W + (size_t)g * 8u * NTOT + n4;
        short8 o0, o1, o2, o3;
#pragma unroll
        for (int r = 0; r < 8; ++r) {
            f32x4 v = __builtin_nontemporal_load((const f32x4*)(src + (size_t)r * NTOT));
            o0[r] = (short)f2bf(v[0]); o1[r] = (short)f2bf(v[1]);
            o2[r] = (short)f2bf(v[2]); o3[r] = (short)f2bf(v[3]);
        }
        short8* dst = (short8*)wp + ((size_t)g * NTOT + n4);
        dst[0] = o0; dst[1] = o1; dst[2] = o2; dst[3] = o3;
    } else {
        int tid = (b - NWG_CONVW) * 256 + (int)threadIdx.x;
        const f32x4* xv = (const f32x4*)x;
        f32x4 a = __builtin_nontemporal_load(xv + 2 * tid);
        f32x4 c = __builtin_nontemporal_load(xv + 2 * tid + 1);
        short8 o;
        o[0] = (short)f2bf(a[0]); o[1] = (short)f2bf(a[1]);
        o[2] = (short)f2bf(a[2]); o[3] = (short)f2bf(a[3]);
        o[4] = (short)f2bf(c[0]); o[5] = (short)f2bf(c[1]);
        o[6] = (short)f2bf(c[2]); o[7] = (short)f2bf(c[3]);
        ((short8*)xb)[tid] = o;
    }
}

__device__ __forceinline__ void gload16(const void* g, void* l) {
    __builtin_amdgcn_global_load_lds(
        (const __attribute__((address_space(1))) void*)g,
        (__attribute__((address_space(3))) void*)l, 16, 0, 0);
}

// C[M][N] = Ab * Wp + bias. R10-champion structure: 128x128 tile, BK=32,
// double-buffered LDS (32 KB), 4 waves 2x2, wave-tile 64x64, 16x16x32 MFMA,
// k-packed conflict-free LDS, gload_lds-then-ds_read order, XCD-banded A,
// LDS-transpose full-line nontemporal epilogue.
// R16 change: __launch_bounds__(256,5) -> 5 blocks/CU (5 x 32 KB = 160 KB =
// exact LDS capacity; VGPR cap 2048/5 ≈ 409 >> kernel's ~100, no spill risk).
// +25% co-resident blocks to fill the per-iteration drain stalls.
__global__ __launch_bounds__(256, 5) void gemm_kernel(
        const unsigned short* __restrict__ Ab,   // [BATCH][D_IN] bf16
        const unsigned short* __restrict__ Bp,   // [64][NTOT][8] bf16 k-packed
        const float* __restrict__ bias,          // [NTOT] fp32
        float* __restrict__ C) {                 // [BATCH][NTOT] fp32
    __shared__ __align__(16) char smem_raw[32768];
    short8 (*sA)[4][128] = reinterpret_cast<short8(*)[4][128]>(smem_raw);          // 16 KB
    short8 (*sB)[4][128] = reinterpret_cast<short8(*)[4][128]>(smem_raw + 16384);  // 16 KB

    const int bid = (int)blockIdx.x;
    const int xcd = bid & 7;
    const int j   = bid >> 3;          // 0..1027
    const int mt  = xcd * 4 + (j & 3); // XCD-exclusive 4-mt A band (512 KB, L2)
    const int nt  = j >> 2;            // 0..256, swept in step across XCDs
    const int brow = mt * 128;
    const int bcol = nt * 128;

    const int tid  = (int)threadIdx.x;
    const int lane = tid & 63;
    const int w    = tid >> 6;      // wave 0..3
    const int wr   = w >> 1;        // wave row (0,1)
    const int wc   = w & 1;         // wave col (0,1)

    f32x4 acc[4][4] = {};

    const unsigned short* gA0 = Ab + (size_t)(brow + lane) * D_IN + w * 8;
    const unsigned short* gA1 = Ab + (size_t)(brow + 64 + lane) * D_IN + w * 8;
    const unsigned short* gB0 = Bp + ((size_t)w * NTOT + bcol + lane) * 8;
    const unsigned short* gB1 = Bp + ((size_t)w * NTOT + bcol + 64 + lane) * 8;
    const size_t bstep = (size_t)4 * NTOT * 8;

    const int g  = lane >> 4;
    const int fr = lane & 15;

    // --- prologue: stage K-tile 0 into buffer 0 ---
    gload16(gA0, (void*)&sA[0][w][0]);
    gload16(gA1, (void*)&sA[0][w][64]);
    gload16(gB0, (void*)&sB[0][w][0]);
    gload16(gB1, (void*)&sB[0][w][64]);
    gA0 += 32; gA1 += 32; gB0 += bstep; gB1 += bstep;
    __syncthreads();

    int cur = 0;
    for (int it = 0; it < 16; ++it) {
        if (it < 15) {
            const int nxt = cur ^ 1;
            gload16(gA0, (void*)&sA[nxt][w][0]);
            gload16(gA1, (void*)&sA[nxt][w][64]);
            gload16(gB0, (void*)&sB[nxt][w][0]);
            gload16(gB1, (void*)&sB[nxt][w][64]);
            gA0 += 32; gA1 += 32; gB0 += bstep; gB1 += bstep;
        }

        short8 aF[4], bF[4];
#pragma unroll
        for (int m = 0; m < 4; ++m) aF[m] = sA[cur][g][wr * 64 + m * 16 + fr];
#pragma unroll
        for (int n = 0; n < 4; ++n) bF[n] = sB[cur][g][wc * 64 + n * 16 + fr];
#pragma unroll
        for (int m = 0; m < 4; ++m)
#pragma unroll
            for (int n = 0; n < 4; ++n)
                acc[m][n] = __builtin_amdgcn_mfma_f32_16x16x32_bf16(
                    aF[m], bF[n], acc[m][n], 0, 0, 0);

        __syncthreads();
        cur ^= 1;
    }
    // final __syncthreads drained all LDS reads -> smem reusable for transpose.

    // ---- epilogue: per-wave LDS transpose -> full-line nt stores ----
    // frag layout: acc[m][n][q] = C[wr*64+m*16+(lane>>4)*4+q][wc*64+n*16+fr]
    const int colb = bcol + wc * 64 + fr;
    float bv[4];
#pragma unroll
    for (int n = 0; n < 4; ++n) bv[n] = bias[colb + n * 16];

    float* tw = reinterpret_cast<float*>(smem_raw) + w * 1088;  // 16 rows x 68
    const int rl = lane >> 3;       // 0..7
    const int c8 = lane & 7;        // 0..7
#pragma unroll
    for (int m = 0; m < 4; ++m) {
#pragma unroll
        for (int n = 0; n < 4; ++n)
#pragma unroll
            for (int q = 0; q < 4; ++q)
                tw[((lane >> 4) * 4 + q) * 68 + fr + 16 * n] = acc[m][n][q] + bv[n];
#pragma unroll
        for (int rg = 0; rg < 2; ++rg)
#pragma unroll
            for (int h = 0; h < 2; ++h) {
                f32x4 v = *(const f32x4*)&tw[(rg * 8 + rl) * 68 + (c8 + 8 * h) * 4];
                float* dst = C + (size_t)(brow + wr * 64 + m * 16 + rg * 8 + rl) * NTOT
                               + bcol + wc * 64 + (c8 + 8 * h) * 4;
                __builtin_nontemporal_store(v, (f32x4*)dst);
            }
    }
}

extern "C" void kernel_launch(void* const* d_in, const int* in_sizes, int n_in,
                              void* d_out, int out_size, void* d_ws, size_t ws_size,
                              hipStream_t stream) {
    const float* x = (const float*)d_in[0];
    const float* W = (const float*)d_in[1];
    const float* b = (const float*)d_in[2];
    float* out = (float*)d_out;

    unsigned short* xb = (unsigned short*)d_ws;               // 4 MB
    unsigned short* wp = xb + (size_t)BATCH * D_IN;           // +33.7 MB

    conv_fused<<<NWG_CONVW + NWG_CONVX, 256, 0, stream>>>(x, W, xb, wp);
    gemm_kernel<<<NWG_GEMM, 256, 0, stream>>>(xb, wp, b, out);
}

// Round 17
// 229.982 us; speedup vs baseline: 3.1191x; 3.1191x over previous
//
#include <hip/hip_runtime.h>
#include <hip/hip_bf16.h>
#include <stdint.h>

#define D_IN    512
#define NTOT    32896
#define BATCH   4096
#define NWG_GEMM 8224   // 32 m-tiles * 257 n-tiles
#define NWG_CONVW 8224  // (64*32896)/256
#define NWG_CONVX 1024  // (4096*512/8)/256

typedef __attribute__((ext_vector_type(8))) short short8;
typedef __attribute__((ext_vector_type(4))) float f32x4;

__device__ __forceinline__ unsigned short f2bf(float f) {
    union { float f; uint32_t u; } v; v.f = f;
    return (unsigned short)((v.u + 0x7fffu + ((v.u >> 16) & 1u)) >> 16);
}

// Fused conversion: blocks [0, NWG_CONVW) convert W -> k-packed bf16,
// blocks [NWG_CONVW, +NWG_CONVX) convert x -> bf16 (fills idle CUs).
__global__ __launch_bounds__(256) void conv_fused(const float* __restrict__ x,
                                                  const float* __restrict__ W,
                                                  unsigned short* __restrict__ xb,
                                                  unsigned short* __restrict__ wp) {
    const int b = (int)blockIdx.x;
    if (b < NWG_CONVW) {
        // W [D_IN][NTOT] fp32 -> Wp[g][n][r] = W[g*8+r][n]
        int tid = b * 256 + (int)threadIdx.x;
        int g = tid / NTOT;
        int n = tid - g * NTOT;
        const float* src = W + (size_t)g * 8u * NTOT + n;
        short8 o;
#pragma unroll
        for (int r = 0; r < 8; ++r)
            o[r] = (short)f2bf(__builtin_nontemporal_load(src + (size_t)r * NTOT));
        ((short8*)wp)[(size_t)g * NTOT + n] = o;
    } else {
        int tid = (b - NWG_CONVW) * 256 + (int)threadIdx.x;
        const f32x4* xv = (const f32x4*)x;
        f32x4 a = __builtin_nontemporal_load(xv + 2 * tid);
        f32x4 c = __builtin_nontemporal_load(xv + 2 * tid + 1);
        short8 o;
        o[0] = (short)f2bf(a[0]); o[1] = (short)f2bf(a[1]);
        o[2] = (short)f2bf(a[2]); o[3] = (short)f2bf(a[3]);
        o[4] = (short)f2bf(c[0]); o[5] = (short)f2bf(c[1]);
        o[6] = (short)f2bf(c[2]); o[7] = (short)f2bf(c[3]);
        ((short8*)xb)[tid] = o;
    }
}

__device__ __forceinline__ void gload16(const void* g, void* l) {
    __builtin_amdgcn_global_load_lds(
        (const __attribute__((address_space(1))) void*)g,
        (__attribute__((address_space(3))) void*)l, 16, 0, 0);
}

// C[M][N] = Ab * Wp + bias. FINAL champion (R10, 228.5 µs): 128x128 tile,
// BK=32, double-buffered LDS (32 KB), 4 waves 2x2, wave-tile 64x64, 16x16x32
// MFMA, k-packed conflict-free LDS (BANK_CONFLICT=0), global_load_lds
// staging, XCD-banded A (each XCD owns a 4-mt band, L2-resident), 4 blocks/CU
// (NOTE: min-waves >= 5 forces VGPR clamp -> spill; (256,4) is the max safe),
// LDS-transpose epilogue -> full-128B-line nontemporal stores (no TCC
// write-allocate fetch).
__global__ __launch_bounds__(256, 4) void gemm_kernel(
        const unsigned short* __restrict__ Ab,   // [BATCH][D_IN] bf16
        const unsigned short* __restrict__ Bp,   // [64][NTOT][8] bf16 k-packed
        const float* __restrict__ bias,          // [NTOT] fp32
        float* __restrict__ C) {                 // [BATCH][NTOT] fp32
    __shared__ __align__(16) char smem_raw[32768];
    short8 (*sA)[4][128] = reinterpret_cast<short8(*)[4][128]>(smem_raw);          // 16 KB
    short8 (*sB)[4][128] = reinterpret_cast<short8(*)[4][128]>(smem_raw + 16384);  // 16 KB

    const int bid = (int)blockIdx.x;
    const int xcd = bid & 7;
    const int j   = bid >> 3;          // 0..1027
    const int mt  = xcd * 4 + (j & 3); // XCD-exclusive 4-mt A band (512 KB, L2)
    const int nt  = j >> 2;            // 0..256, swept in step across XCDs
    const int brow = mt * 128;
    const int bcol = nt * 128;

    const int tid  = (int)threadIdx.x;
    const int lane = tid & 63;
    const int w    = tid >> 6;      // wave 0..3
    const int wr   = w >> 1;        // wave row (0,1)
    const int wc   = w & 1;         // wave col (0,1)

    f32x4 acc[4][4] = {};

    const unsigned short* gA0 = Ab + (size_t)(brow + lane) * D_IN + w * 8;
    const unsigned short* gA1 = Ab + (size_t)(brow + 64 + lane) * D_IN + w * 8;
    const unsigned short* gB0 = Bp + ((size_t)w * NTOT + bcol + lane) * 8;
    const unsigned short* gB1 = Bp + ((size_t)w * NTOT + bcol + 64 + lane) * 8;
    const size_t bstep = (size_t)4 * NTOT * 8;

    const int g  = lane >> 4;
    const int fr = lane & 15;

    // --- prologue: stage K-tile 0 into buffer 0 ---
    gload16(gA0, (void*)&sA[0][w][0]);
    gload16(gA1, (void*)&sA[0][w][64]);
    gload16(gB0, (void*)&sB[0][w][0]);
    gload16(gB1, (void*)&sB[0][w][64]);
    gA0 += 32; gA1 += 32; gB0 += bstep; gB1 += bstep;
    __syncthreads();

    int cur = 0;
    for (int it = 0; it < 16; ++it) {
        if (it < 15) {
            const int nxt = cur ^ 1;
            gload16(gA0, (void*)&sA[nxt][w][0]);
            gload16(gA1, (void*)&sA[nxt][w][64]);
            gload16(gB0, (void*)&sB[nxt][w][0]);
            gload16(gB1, (void*)&sB[nxt][w][64]);
            gA0 += 32; gA1 += 32; gB0 += bstep; gB1 += bstep;
        }

        short8 aF[4], bF[4];
#pragma unroll
        for (int m = 0; m < 4; ++m) aF[m] = sA[cur][g][wr * 64 + m * 16 + fr];
#pragma unroll
        for (int n = 0; n < 4; ++n) bF[n] = sB[cur][g][wc * 64 + n * 16 + fr];
#pragma unroll
        for (int m = 0; m < 4; ++m)
#pragma unroll
            for (int n = 0; n < 4; ++n)
                acc[m][n] = __builtin_amdgcn_mfma_f32_16x16x32_bf16(
                    aF[m], bF[n], acc[m][n], 0, 0, 0);

        __syncthreads();
        cur ^= 1;
    }
    // final __syncthreads drained all LDS reads -> smem reusable for transpose.

    // ---- epilogue: per-wave LDS transpose -> full-line nt stores ----
    // frag layout: acc[m][n][q] = C[wr*64+m*16+(lane>>4)*4+q][wc*64+n*16+fr]
    const int colb = bcol + wc * 64 + fr;
    float bv[4];
#pragma unroll
    for (int n = 0; n < 4; ++n) bv[n] = bias[colb + n * 16];

    float* tw = reinterpret_cast<float*>(smem_raw) + w * 1088;  // 16 rows x 68
    const int rl = lane >> 3;       // 0..7
    const int c8 = lane & 7;        // 0..7
#pragma unroll
    for (int m = 0; m < 4; ++m) {
#pragma unroll
        for (int n = 0; n < 4; ++n)
#pragma unroll
            for (int q = 0; q < 4; ++q)
                tw[((lane >> 4) * 4 + q) * 68 + fr + 16 * n] = acc[m][n][q] + bv[n];
#pragma unroll
        for (int rg = 0; rg < 2; ++rg)
#pragma unroll
            for (int h = 0; h < 2; ++h) {
                f32x4 v = *(const f32x4*)&tw[(rg * 8 + rl) * 68 + (c8 + 8 * h) * 4];
                float* dst = C + (size_t)(brow + wr * 64 + m * 16 + rg * 8 + rl) * NTOT
                               + bcol + wc * 64 + (c8 + 8 * h) * 4;
                __builtin_nontemporal_store(v, (f32x4*)dst);
            }
    }
}

extern "C" void kernel_launch(void* const* d_in, const int* in_sizes, int n_in,
                              void* d_out, int out_size, void* d_ws, size_t ws_size,
                              hipStream_t stream) {
    const float* x = (const float*)d_in[0];
    const float* W = (const float*)d_in[1];
    const float* b = (const float*)d_in[2];
    float* out = (float*)d_out;

    unsigned short* xb = (unsigned short*)d_ws;               // 4 MB
    unsigned short* wp = xb + (size_t)BATCH * D_IN;           // +33.7 MB

    conv_fused<<<NWG_CONVW + NWG_CONVX, 256, 0, stream>>>(x, W, xb, wp);
    gemm_kernel<<<NWG_GEMM, 256, 0, stream>>>(xb, wp, b, out);
}